// Round 1
// baseline (420.167 us; speedup 1.0000x reference)
//
#include <hip/hip_runtime.h>
#include <math.h>

// One thread per batch element. All small weights staged/precomputed in LDS.
__device__ __forceinline__ void nearest_d8(const float* xx, float* y) {
  float f[8], err[8];
#pragma unroll
  for (int d = 0; d < 8; ++d) { f[d] = rintf(xx[d]); err[d] = xx[d] - f[d]; }
  int idx = 0; float best = -1.0f;
#pragma unroll
  for (int d = 0; d < 8; ++d) { float a = fabsf(err[d]); if (a > best) { best = a; idx = d; } }
  float fs = 0.f;
#pragma unroll
  for (int d = 0; d < 8; ++d) fs += f[d];
  bool ok = ((((int)fs) & 1) == 0);   // mod(f.sum,2)==0  (exact small ints)
#pragma unroll
  for (int d = 0; d < 8; ++d) {
    float g = f[d] + ((d == idx) ? ((err[d] >= 0.f) ? 1.f : -1.f) : 0.f);
    y[d] = ok ? f[d] : g;
  }
}

extern "C" __global__ void __launch_bounds__(256)
e8_kernel(const float* __restrict__ colony, const float* __restrict__ conf,
          const float* __restrict__ Wq, const float* __restrict__ bq,
          const float* __restrict__ Wk, const float* __restrict__ bk,
          const float* __restrict__ Wv, const float* __restrict__ bv,
          const float* __restrict__ comm, const float* __restrict__ role,
          const float* __restrict__ mha_w, const float* __restrict__ mha_b,
          const float* __restrict__ W1, const float* __restrict__ b1,
          const float* __restrict__ W2, const float* __restrict__ b2,
          const float* __restrict__ gate, float* __restrict__ out, int B)
{
  __shared__ float sM8[64], sU[8], sV[8], sCc[1];
  __shared__ float sComm[49], sRole[7];
  __shared__ float sWq3[64], sWk3[64], sBq3[8], sBk3[8];
  __shared__ float sWv[64], sBv[8];
  __shared__ float sW1[256], sB1[32], sW2[256], sB2[8];
  __shared__ float sGate[1];

  const int t = threadIdx.x;
  if (t < 64) {
    int i = t >> 3, j = t & 7;
    float a = 0.f;
    for (int h = 0; h < 32; ++h) a += Wq[h * 8 + i] * Wk[h * 8 + j];
    sM8[t] = a;
    sWq3[t] = mha_w[t];
    sWk3[t] = mha_w[64 + t];
    sWv[t] = Wv[t];
  } else if (t < 72) {
    int j = t - 64;
    float a = 0.f, bb = 0.f;
    for (int h = 0; h < 32; ++h) { a += bq[h] * Wk[h * 8 + j]; bb += bk[h] * Wq[h * 8 + j]; }
    sU[j] = a; sV[j] = bb;
    sBq3[j] = mha_b[j]; sBk3[j] = mha_b[8 + j]; sBv[j] = bv[j]; sB2[j] = b2[j];
  } else if (t == 72) {
    float c = 0.f;
    for (int h = 0; h < 32; ++h) c += bq[h] * bk[h];
    sCc[0] = c;
    sGate[0] = 1.f / (1.f + expf(-gate[0]));
  } else if (t >= 80 && t < 87) {
    int n = t - 80;
    float mx = -1e30f;
    for (int m = 0; m < 7; ++m) mx = fmaxf(mx, comm[n * 7 + m]);
    float e[7], s = 0.f;
    for (int m = 0; m < 7; ++m) { e[m] = expf(comm[n * 7 + m] - mx); s += e[m]; }
    for (int m = 0; m < 7; ++m) sComm[n * 7 + m] = e[m] / s;
  } else if (t == 87) {
    float mx = -1e30f;
    for (int m = 0; m < 7; ++m) mx = fmaxf(mx, role[m]);
    float e[7], s = 0.f;
    for (int m = 0; m < 7; ++m) { e[m] = expf(role[m] - mx); s += e[m]; }
    for (int m = 0; m < 7; ++m) sRole[m] = e[m] / s;
  }
  sW1[t] = W1[t];
  sW2[t] = W2[t];
  if (t < 32) sB1[t] = b1[t];
  __syncthreads();

  const int b = blockIdx.x * 256 + t;
  if (b >= B) return;

  // ---- load + normalize x (7 rows of 8) ----
  const float* px = colony + (size_t)b * 56;
  float x[7][8];
#pragma unroll
  for (int n = 0; n < 7; ++n) {
    float4 v0 = *(const float4*)(px + n * 8);
    float4 v1 = *(const float4*)(px + n * 8 + 4);
    x[n][0] = v0.x; x[n][1] = v0.y; x[n][2] = v0.z; x[n][3] = v0.w;
    x[n][4] = v1.x; x[n][5] = v1.y; x[n][6] = v1.z; x[n][7] = v1.w;
    float ss = 0.f;
#pragma unroll
    for (int d = 0; d < 8; ++d) ss += x[n][d] * x[n][d];
    float nrm = fmaxf(sqrtf(ss), 1e-12f);
#pragma unroll
    for (int d = 0; d < 8; ++d) x[n][d] = x[n][d] / nrm;
  }

  // ---- mean over n ----
  float xm[8];
#pragma unroll
  for (int d = 0; d < 8; ++d) {
    float s = 0.f;
#pragma unroll
    for (int n = 0; n < 7; ++n) s += x[n][d];
    xm[d] = s / 7.0f;
  }

  // ---- scores via collapsed q·k ----
  float w8[8];
#pragma unroll
  for (int j = 0; j < 8; ++j) {
    float a = 0.f;
#pragma unroll
    for (int i = 0; i < 8; ++i) a += xm[i] * sM8[i * 8 + j];
    w8[j] = a + sU[j];
  }
  float base = sCc[0];
#pragma unroll
  for (int i = 0; i < 8; ++i) base += sV[i] * xm[i];
  float sc[7];
#pragma unroll
  for (int n = 0; n < 7; ++n) {
    float a = base;
#pragma unroll
    for (int j = 0; j < 8; ++j) a += w8[j] * x[n][j];
    sc[n] = a / 5.656854249492381f;   // / sqrt(32)
  }
  float sc2[7];
#pragma unroll
  for (int m = 0; m < 7; ++m) {
    float a = 0.f;
#pragma unroll
    for (int n = 0; n < 7; ++n) a += sc[n] * sComm[n * 7 + m];
    sc2[m] = a + sRole[m];
  }

  // ---- tiny 4-head MHA over the 7 colonies ----
  float K[7][8];
#pragma unroll
  for (int m = 0; m < 7; ++m) {
#pragma unroll
    for (int r = 0; r < 8; ++r) {
      float a = sBk3[r];
#pragma unroll
      for (int j = 0; j < 8; ++j) a += x[m][j] * sWk3[r * 8 + j];
      K[m][r] = a;
    }
  }
  float mhs[7];
#pragma unroll
  for (int m = 0; m < 7; ++m) mhs[m] = 0.f;
#pragma unroll
  for (int n = 0; n < 7; ++n) {
    float Qn[8];
#pragma unroll
    for (int r = 0; r < 8; ++r) {
      float a = sBq3[r];
#pragma unroll
      for (int j = 0; j < 8; ++j) a += x[n][j] * sWq3[r * 8 + j];
      Qn[r] = a;
    }
#pragma unroll
    for (int h = 0; h < 4; ++h) {
      float lg[7], mx = -1e30f;
#pragma unroll
      for (int m = 0; m < 7; ++m) {
        float a = Qn[2 * h] * K[m][2 * h] + Qn[2 * h + 1] * K[m][2 * h + 1];
        lg[m] = a / 1.4142135623730951f;  // / sqrt(2)
        mx = fmaxf(mx, lg[m]);
      }
      float e[7], s = 0.f;
#pragma unroll
      for (int m = 0; m < 7; ++m) { e[m] = expf(lg[m] - mx); s += e[m]; }
#pragma unroll
      for (int m = 0; m < 7; ++m) mhs[m] += e[m] / s;
    }
  }

  // ---- combine scores, softmax, confidence re-norm ----
  float scf[7], mx = -1e30f;
#pragma unroll
  for (int m = 0; m < 7; ++m) {
    scf[m] = 0.7f * sc2[m] + 0.3f * ((mhs[m] / 4.0f) / 7.0f);
    mx = fmaxf(mx, scf[m]);
  }
  float e[7], s = 0.f;
#pragma unroll
  for (int m = 0; m < 7; ++m) { e[m] = expf(scf[m] - mx); s += e[m]; }
  float w[7], ws = 0.f;
  const float* pc = conf + (size_t)b * 7;
#pragma unroll
  for (int m = 0; m < 7; ++m) { w[m] = (e[m] / s) * pc[m]; ws += w[m]; }
  float den = fmaxf(ws, 1e-8f);
#pragma unroll
  for (int m = 0; m < 7; ++m) w[m] = w[m] / den;

  // ---- combined = Wv (Σ w_n x_n) + bv ----
  float xc[8];
#pragma unroll
  for (int d = 0; d < 8; ++d) {
    float a = 0.f;
#pragma unroll
    for (int n = 0; n < 7; ++n) a += w[n] * x[n][d];
    xc[d] = a;
  }
  float comb[8];
#pragma unroll
  for (int i = 0; i < 8; ++i) {
    float a = sBv[i];
#pragma unroll
    for (int j = 0; j < 8; ++j) a += sWv[i * 8 + j] * xc[j];
    comb[i] = a;
  }

  // ---- MLP: gelu(exact) ----
  float o8[8];
#pragma unroll
  for (int i = 0; i < 8; ++i) o8[i] = sB2[i];
#pragma unroll
  for (int i = 0; i < 32; ++i) {
    float a = sB1[i];
#pragma unroll
    for (int j = 0; j < 8; ++j) a += sW1[i * 8 + j] * comb[j];
    float g = 0.5f * a * (1.f + erff(a / 1.4142135623730951f));
#pragma unroll
    for (int k = 0; k < 8; ++k) o8[k] += sW2[k * 32 + i] * g;
  }

  // ---- refined = norm(combined + sigmoid(gate)*h) ----
  float gsig = sGate[0];
  float pre[8], ss2 = 0.f;
#pragma unroll
  for (int d = 0; d < 8; ++d) { pre[d] = comb[d] + gsig * o8[d]; ss2 += pre[d] * pre[d]; }
  float nrm2 = fmaxf(sqrtf(ss2), 1e-12f);
  float r[8];
#pragma unroll
  for (int d = 0; d < 8; ++d) r[d] = pre[d] / nrm2;

  // ---- nearest E8 point (quantized == hard) ----
  float y0[8], y1[8], xs[8];
  nearest_d8(r, y0);
#pragma unroll
  for (int d = 0; d < 8; ++d) xs[d] = r[d] - 0.5f;
  nearest_d8(xs, y1);
#pragma unroll
  for (int d = 0; d < 8; ++d) y1[d] += 0.5f;
  float d0 = 0.f, d1 = 0.f;
#pragma unroll
  for (int d = 0; d < 8; ++d) {
    float a = r[d] - y0[d], bb = r[d] - y1[d];
    d0 += a * a; d1 += bb * bb;
  }
  bool use0 = (d0 <= d1);
  float hard[8];
#pragma unroll
  for (int d = 0; d < 8; ++d) hard[d] = use0 ? y0[d] : y1[d];

  // ---- argmin over 240 E8 roots: sq = (ssum - 2*dot) + 2, first-min wins ----
  float ssum = 0.f;
#pragma unroll
  for (int d = 0; d < 8; ++d) ssum += r[d] * r[d];
  int bestIdx = 0; float bestSq = 1e30f;
  int idx = 0;
#pragma unroll
  for (int i = 0; i < 8; ++i) {
#pragma unroll
    for (int j = i + 1; j < 8; ++j) {
#pragma unroll
      for (int s4 = 0; s4 < 4; ++s4) {
        float si = (s4 & 2) ? -1.f : 1.f;
        float sj = (s4 & 1) ? -1.f : 1.f;
        float dot = si * r[i] + sj * r[j];
        float tt = 2.f * dot;
        float sq = (ssum - tt) + 2.f;
        if (sq < bestSq) { bestSq = sq; bestIdx = idx; }
        ++idx;
      }
    }
  }
  float hr[8];
#pragma unroll
  for (int d = 0; d < 8; ++d) hr[d] = 0.5f * r[d];   // exact
#pragma unroll
  for (int k = 0; k < 128; ++k) {
    int c = (k << 1) | (__popc(k) & 1);   // even-parity masks ascending
    float dot = 0.f;
#pragma unroll
    for (int d = 0; d < 8; ++d) dot += ((c >> (7 - d)) & 1) ? -hr[d] : hr[d];
    float tt = 2.f * dot;
    float sq = (ssum - tt) + 2.f;
    if (sq < bestSq) { bestSq = sq; bestIdx = 112 + k; }
  }

  // ---- outputs: quantized (B,8) | indices (B,) | weights (B,7) ----
  float* outq = out;
  float* outi = out + (size_t)B * 8;
  float* outw = out + (size_t)B * 9;
  float q0[8];
#pragma unroll
  for (int d = 0; d < 8; ++d) q0[d] = r[d] + (hard[d] - r[d]);
  float4 qa = make_float4(q0[0], q0[1], q0[2], q0[3]);
  float4 qb = make_float4(q0[4], q0[5], q0[6], q0[7]);
  *(float4*)(outq + (size_t)b * 8) = qa;
  *(float4*)(outq + (size_t)b * 8 + 4) = qb;
  outi[b] = (float)bestIdx;
#pragma unroll
  for (int m = 0; m < 7; ++m) outw[(size_t)b * 7 + m] = w[m];
}

extern "C" void kernel_launch(void* const* d_in, const int* in_sizes, int n_in,
                              void* d_out, int out_size, void* d_ws, size_t ws_size,
                              hipStream_t stream) {
  const float* colony = (const float*)d_in[0];
  const float* conf   = (const float*)d_in[1];
  const float* Wq     = (const float*)d_in[2];
  const float* bq     = (const float*)d_in[3];
  const float* Wk     = (const float*)d_in[4];
  const float* bk     = (const float*)d_in[5];
  const float* Wv     = (const float*)d_in[6];
  const float* bv     = (const float*)d_in[7];
  const float* comm   = (const float*)d_in[8];
  const float* role   = (const float*)d_in[9];
  const float* mhaw   = (const float*)d_in[10];
  const float* mhab   = (const float*)d_in[11];
  const float* W1     = (const float*)d_in[12];
  const float* b1     = (const float*)d_in[13];
  const float* W2     = (const float*)d_in[14];
  const float* b2     = (const float*)d_in[15];
  const float* gate   = (const float*)d_in[16];

  int B = in_sizes[0] / 56;
  dim3 grid((B + 255) / 256), block(256);
  hipLaunchKernelGGL(e8_kernel, grid, block, 0, stream,
                     colony, conf, Wq, bq, Wk, bk, Wv, bv, comm, role,
                     mhaw, mhab, W1, b1, W2, b2, gate, (float*)d_out, B);
}